// Round 4
// baseline (224.265 us; speedup 1.0000x reference)
//
#include <hip/hip_runtime.h>
#include <hip/hip_bf16.h>

// GCN 2-layer via CSR gather:
//   dis = rsqrt(indeg_by_dst + 1)
//   hs  = bf16( (x@W) * dis[row] )     (split-bf16 MFMA, fp32-accurate)
//   out[i] = act( dis[i] * (hs[i] + sum_{s in N(i)} hs[s]) + b )
// CSR build is a fully DETERMINISTIC two-pass multisplit (radix-sort style).
// GEMM is MFMA (16x16x32 bf16) with 2-term split of X and W:
//   x@W = xh@Wh + xh@Wl + xl@Wh  (+ xl@Wl ~ 2^-18, dropped)
// R3: csr_gemm rebalanced -- BW 256->128 (782 blocks x 256 thr, ~3/CU all
// resident vs 391x512 at 1.5/CU half-starved), LDS ladder scan (16 barriers)
// -> wave shfl_up scan (4 barriers total), ebuf staging issued before the
// gcnt scalar load resolves (masked after). MFMA order per row unchanged ->
// bit-identical hs. Aggregates untouched this round.

#define FOUT 64
#define BW 128        // nodes per bucket
#define BSH 7
#define MAXB 1024     // >= ceil(n/BW), power of 2
#define CHUNK 4096    // edges per hist/place block; nblk = ceil(E/CHUNK) <= 512
#define SLAB 3072     // slab capacity per bucket (mean 2046 for E=1.6M,B=782)

#define NT1 1024      // W1 frag tasks: (128/32)*4*64
#define NT2 512       // W2 frag tasks: (64/32)*4*64

__device__ __forceinline__ float bf2f(unsigned int u16) {
    union { unsigned int i; float f; } c;
    c.i = u16 << 16;
    return c.f;
}
__device__ __forceinline__ unsigned short f2bf(float f) {
    union { float f; unsigned int i; } c;
    c.f = f;
    unsigned int i = c.i;
    return (unsigned short)((i + 0x7FFFu + ((i >> 16) & 1u)) >> 16);  // RN-even
}

typedef __attribute__((ext_vector_type(8))) short short8v;  // 8 bf16 = 4 VGPR
typedef __attribute__((ext_vector_type(4))) float f32x4;    // MFMA acc

// ---- split fp32x8 -> bf16 hi/lo A-fragments ------------------------------
__device__ __forceinline__ void split_frag(const float* xa, short8v* Ah, short8v* Al) {
    union { unsigned int u[4]; short8v v; } H, L;
#pragma unroll
    for (int p = 0; p < 4; p++) {
        unsigned short h0 = f2bf(xa[2 * p]);
        unsigned short h1 = f2bf(xa[2 * p + 1]);
        H.u[p] = (unsigned int)h0 | ((unsigned int)h1 << 16);
        unsigned short l0 = f2bf(xa[2 * p] - bf2f(h0));
        unsigned short l1 = f2bf(xa[2 * p + 1] - bf2f(h1));
        L.u[p] = (unsigned int)l0 | ((unsigned int)l1 << 16);
    }
    *Ah = H.v;
    *Al = L.v;
}

// ---- W -> fragment-linear bf16 hi/lo split ------------------------------
// task = ((s*4 + cf)*64 + lane); element j of lane's B-frag is
// W[s*32 + (lane>>4)*8 + j][cf*16 + (lane&15)]  (same k-mapping as A-frags,
// so any internal k-permutation of the MFMA cancels between A and B).
__device__ __forceinline__ void conv_w_frag(const float* __restrict__ W,
                                            unsigned short* __restrict__ WhF,
                                            unsigned short* __restrict__ WlF,
                                            int task) {
    const int lane = task & 63;
    const int cf = (task >> 6) & 3;
    const int s = task >> 8;
    const int q = lane >> 4, m = lane & 15;
#pragma unroll
    for (int j = 0; j < 8; j++) {
        int k = s * 32 + q * 8 + j;
        float x = W[(size_t)k * 64 + cf * 16 + m];
        unsigned short h = f2bf(x);
        WhF[(size_t)task * 8 + j] = h;
        WlF[(size_t)task * 8 + j] = f2bf(x - bf2f(h));
    }
}

// ---- pass A: per-block bucket histogram -> cnt[blk][bucket] --------------
// block 0 additionally pre-splits W1/W2 into frag-linear bf16 hi/lo tables.
__global__ __launch_bounds__(512) void edge_hist(
    const int* __restrict__ dst, int* __restrict__ cnt, int E,
    const float* __restrict__ W1, const float* __restrict__ W2,
    unsigned short* __restrict__ whf1, unsigned short* __restrict__ wlf1,
    unsigned short* __restrict__ whf2, unsigned short* __restrict__ wlf2) {
    __shared__ int h[MAXB];
    const int blk = blockIdx.x, t = threadIdx.x;
    h[t] = 0;
    h[t + 512] = 0;
    __syncthreads();
    const int e0 = blk * CHUNK;
#pragma unroll
    for (int k = 0; k < CHUNK / 512; k++) {
        int e = e0 + k * 512 + t;
        if (e < E) atomicAdd(&h[dst[e] >> BSH], 1);
    }
    if (blk == 0) {
        for (int task = t; task < NT1 + NT2; task += 512) {
            if (task < NT1) conv_w_frag(W1, whf1, wlf1, task);
            else            conv_w_frag(W2, whf2, wlf2, task - NT1);
        }
    }
    __syncthreads();
    cnt[blk * MAXB + t] = h[t];
    cnt[blk * MAXB + t + 512] = h[t + 512];
}

// ---- pass B: per-bucket exclusive scan over blocks -> absolute bases -----
__global__ __launch_bounds__(512) void col_scan(int* __restrict__ cnt, int nblk,
                                                int* __restrict__ gcnt) {
    __shared__ int ts[512];
    const int b = blockIdx.x;  // bucket
    const int t = threadIdx.x;
    int v = (t < nblk) ? cnt[t * MAXB + b] : 0;
    ts[t] = v;
    __syncthreads();
    for (int off = 1; off < 512; off <<= 1) {
        int x = (t >= off) ? ts[t - off] : 0;
        __syncthreads();
        ts[t] += x;
        __syncthreads();
    }
    if (t < nblk) cnt[t * MAXB + b] = b * SLAB + ts[t] - v;  // abs base
    if (t == 511) gcnt[b] = ts[511];                          // bucket total
}

// ---- pass C: placement at precomputed bases (no global atomics) ----------
__global__ __launch_bounds__(512) void edge_place(
    const int* __restrict__ src, const int* __restrict__ dst,
    const int* __restrict__ cnt, int* __restrict__ ebuf, int E) {
    __shared__ int lbase[MAXB];
    __shared__ int cur[MAXB];
    const int blk = blockIdx.x, t = threadIdx.x;
    lbase[t] = cnt[blk * MAXB + t];
    lbase[t + 512] = cnt[blk * MAXB + t + 512];
    cur[t] = 0;
    cur[t + 512] = 0;
    __syncthreads();
    const int e0 = blk * CHUNK;
#pragma unroll
    for (int k = 0; k < CHUNK / 512; k++) {
        int e = e0 + k * 512 + t;
        if (e < E) {
            int d = dst[e];
            int b = d >> BSH;
            int r = atomicAdd(&cur[b], 1);  // LDS only
            ebuf[lbase[b] + r] = src[e] | ((d & (BW - 1)) << 17);  // src < 2^17
        }
    }
}

// ---- fused: per-bucket CSR finalize + gemm1 for the bucket's 128 rows ----
// 256 threads. Stage loads are UNGUARDED (issued before gcnt resolves,
// masked after). Rank scan is wave-level shfl_up (4 barriers total).
// gemm1: 4 waves x 2 tiles of 16 rows, split-bf16 MFMA.
template <int K>
__global__ __launch_bounds__(256) void csr_gemm(
    int* __restrict__ ebuf, const int* __restrict__ gcnt,
    unsigned int* __restrict__ rowinfo, float* __restrict__ dis, int n,
    const float* __restrict__ X, const unsigned short* __restrict__ WhF,
    const unsigned short* __restrict__ WlF, unsigned short* __restrict__ HS) {
    __shared__ int ldeg[BW];
    __shared__ float sdis[BW];
    __shared__ int wtot[2];
    const int b = blockIdx.x, t = threadIdx.x;
    const int node0 = b << BSH;
    const int nn = min(BW, n - node0);
    const int ebeg = b * SLAB;

    // stage slab words unguarded -- no dependency on gcnt (mask later)
    int raw[SLAB / 256];
#pragma unroll
    for (int k = 0; k < SLAB / 256; k++) raw[k] = ebuf[ebeg + t + k * 256];

    const int cnt = gcnt[b];
    if (t < BW) ldeg[t] = 0;
    __syncthreads();  // B1

    int w[SLAB / 256];
#pragma unroll
    for (int k = 0; k < SLAB / 256; k++) {
        w[k] = (t + k * 256 < cnt) ? raw[k] : -1;
        if (w[k] >= 0) atomicAdd(&ldeg[w[k] >> 17], 1);
    }
    __syncthreads();  // B2

    int v = 0, pv = 0;
    if (t < BW) { v = ldeg[t]; pv = v; }
    // inclusive scan of ldeg[0..BW) -- waves 0,1 via shfl_up, combine in LDS
#pragma unroll
    for (int d = 1; d < 64; d <<= 1) {
        int x = __shfl_up(pv, d);
        if ((t & 63) >= d) pv += x;
    }
    if (t < BW && (t & 63) == 63) wtot[t >> 6] = pv;
    __syncthreads();  // B3
    if (t < BW && t >= 64) pv += wtot[0];
    const int ex = pv - v;  // exclusive prefix within bucket
    if (t < nn) {
        rowinfo[node0 + t] = ((unsigned int)(ebeg + ex) << 8) | (unsigned int)v;
        float dv = rsqrtf((float)v + 1.0f);  // +1 self-loop
        dis[node0 + t] = dv;
        sdis[t] = dv;
    } else if (t < BW) {
        sdis[t] = 0.f;
    }
    if (t < BW) ldeg[t] = ex;  // reuse as write cursor (all reads of ldeg done)
    __syncthreads();  // B4
#pragma unroll
    for (int k = 0; k < SLAB / 256; k++)
        if (w[k] >= 0) {
            int r = atomicAdd(&ldeg[w[k] >> 17], 1);
            ebuf[ebeg + r] = w[k] & 0x1FFFF;  // ebuf becomes col
        }

    // ---- gemm1 for rows [node0, node0+128). sdis valid since B4; gemm
    // touches neither ebuf nor ldeg, so no further barrier needed.
    const int lane = t & 63;
    const int wvv = t >> 6;                 // 4 waves
    const int m = lane & 15;                // A row-in-tile / D col
    const int q = lane >> 4;                // A k-group / D row-quad
#pragma unroll 1
    for (int t2 = 0; t2 < 2; t2++) {
        const int tile = wvv * 2 + t2;      // 0..7
        const int wrow0 = node0 + tile * 16;
        f32x4 acc[4];
#pragma unroll
        for (int cf = 0; cf < 4; cf++) acc[cf] = (f32x4)0.f;

        const int arow = wrow0 + m;
        const bool rok = (arow < n);
        const float* xp = X + (size_t)arow * K + q * 8;
#pragma unroll
        for (int s = 0; s < K / 32; s++) {
            float4 v0, v1;
            if (rok) {
                v0 = *(const float4*)(xp + s * 32);
                v1 = *(const float4*)(xp + s * 32 + 4);
            } else {
                v0 = make_float4(0.f, 0.f, 0.f, 0.f);
                v1 = v0;
            }
            const float xa[8] = {v0.x, v0.y, v0.z, v0.w, v1.x, v1.y, v1.z, v1.w};
            short8v Ah, Al;
            split_frag(xa, &Ah, &Al);
            const unsigned short* wh = WhF + ((size_t)(s * 4) * 64 + lane) * 8;
            const unsigned short* wl = WlF + ((size_t)(s * 4) * 64 + lane) * 8;
#pragma unroll
            for (int cf = 0; cf < 4; cf++) {
                short8v bh = *(const short8v*)(wh + (size_t)cf * 64 * 8);
                short8v bl = *(const short8v*)(wl + (size_t)cf * 64 * 8);
                acc[cf] = __builtin_amdgcn_mfma_f32_16x16x32_bf16(Ah, bh, acc[cf], 0, 0, 0);
                acc[cf] = __builtin_amdgcn_mfma_f32_16x16x32_bf16(Al, bh, acc[cf], 0, 0, 0);
                acc[cf] = __builtin_amdgcn_mfma_f32_16x16x32_bf16(Ah, bl, acc[cf], 0, 0, 0);
            }
        }
        // D: row = wrow0 + 4*q + r, col = cf*16 + m
#pragma unroll
        for (int r = 0; r < 4; r++) {
            int row = wrow0 + q * 4 + r;
            if (row < n) {
                float dr = sdis[tile * 16 + q * 4 + r];
#pragma unroll
                for (int cf = 0; cf < 4; cf++) {
                    HS[(size_t)row * FOUT + cf * 16 + m] = f2bf(acc[cf][r] * dr);
                }
            }
        }
    }
}

// ---- aggregate helpers ---------------------------------------------------
__device__ __forceinline__ void acc8(const uint4 u, float* a) {
    a[0] += bf2f(u.x & 0xFFFFu); a[1] += bf2f(u.x >> 16);
    a[2] += bf2f(u.y & 0xFFFFu); a[3] += bf2f(u.y >> 16);
    a[4] += bf2f(u.z & 0xFFFFu); a[5] += bf2f(u.z >> 16);
    a[6] += bf2f(u.w & 0xFFFFu); a[7] += bf2f(u.w >> 16);
}

// ---- fused: aggregate1 (+relu) -> LDS -> gemm2 -> hs2 --------------------
// 256 threads = 4 waves = 32 nodes (8-lane group per node, uint4 per lane).
// out1 rows live only in LDS. MFMA sequence per accumulator identical to a
// standalone gemm2 -> bit-identical hs2.
#define OSTR 68
__global__ __launch_bounds__(256) void agg_gemm(
    const uint4* __restrict__ hsv, const unsigned int* __restrict__ rowinfo,
    const int* __restrict__ col, const float* __restrict__ dis,
    const float* __restrict__ bias,
    const unsigned short* __restrict__ WhF2, const unsigned short* __restrict__ WlF2,
    unsigned short* __restrict__ HS2, int n) {
    __shared__ float so[32 * OSTR];  // 8704 B
    const int tid = threadIdx.x;
    const int wv = tid >> 6;
    const int lane = tid & 63;
    const int g = lane >> 3;        // group 0..7 -> node
    const int jj = lane & 7;        // uint4 index within row (feats 8jj..8jj+7)
    const int lrow = wv * 8 + g;    // 0..31
    const int i = blockIdx.x * 32 + lrow;

    float o[8];
#pragma unroll
    for (int p = 0; p < 8; p++) o[p] = 0.f;

    if (i < n) {
        const unsigned int info = rowinfo[i];
        const int beg = (int)(info >> 8);
        const int end = beg + (int)(info & 255u);

        float a[8];
        {
            uint4 su = hsv[(size_t)i * 8 + jj];  // self-loop term
            a[0] = bf2f(su.x & 0xFFFFu); a[1] = bf2f(su.x >> 16);
            a[2] = bf2f(su.y & 0xFFFFu); a[3] = bf2f(su.y >> 16);
            a[4] = bf2f(su.z & 0xFFFFu); a[5] = bf2f(su.z >> 16);
            a[6] = bf2f(su.w & 0xFFFFu); a[7] = bf2f(su.w >> 16);
        }
        const int gb = g << 3;
        for (int chunk = beg; chunk < end; chunk += 8) {
            int m = end - chunk;
            if (m > 8) m = 8;
            int c = (chunk + jj < end) ? col[chunk + jj] : 0;
            int q = 0;
            for (; q + 4 <= m; q += 4) {
                int s0 = __shfl(c, gb + q);
                int s1 = __shfl(c, gb + q + 1);
                int s2 = __shfl(c, gb + q + 2);
                int s3 = __shfl(c, gb + q + 3);
                uint4 u0 = hsv[(size_t)s0 * 8 + jj];
                uint4 u1 = hsv[(size_t)s1 * 8 + jj];
                uint4 u2 = hsv[(size_t)s2 * 8 + jj];
                uint4 u3 = hsv[(size_t)s3 * 8 + jj];
                acc8(u0, a);
                acc8(u1, a);
                acc8(u2, a);
                acc8(u3, a);
            }
            for (; q < m; q++) {
                int s = __shfl(c, gb + q);
                acc8(hsv[(size_t)s * 8 + jj], a);
            }
        }
        float d = dis[i];
        const float4* b4 = (const float4*)bias;
        float4 bb0 = b4[jj * 2];
        float4 bb1 = b4[jj * 2 + 1];
        o[0] = fmaxf(d * a[0] + bb0.x, 0.f);
        o[1] = fmaxf(d * a[1] + bb0.y, 0.f);
        o[2] = fmaxf(d * a[2] + bb0.z, 0.f);
        o[3] = fmaxf(d * a[3] + bb0.w, 0.f);
        o[4] = fmaxf(d * a[4] + bb1.x, 0.f);
        o[5] = fmaxf(d * a[5] + bb1.y, 0.f);
        o[6] = fmaxf(d * a[6] + bb1.z, 0.f);
        o[7] = fmaxf(d * a[7] + bb1.w, 0.f);
    }
    {
        float* sp = &so[lrow * OSTR + jj * 8];
        *(float4*)sp = make_float4(o[0], o[1], o[2], o[3]);
        *(float4*)(sp + 4) = make_float4(o[4], o[5], o[6], o[7]);
    }
    __syncthreads();

    // ---- gemm2 from LDS: hs2 = bf16((out1 @ W2) * dis) ------------------
    const int tile = wv >> 1;       // 0..1 (16-row tile)
    const int ch = wv & 1;          // col half: cf in {2ch, 2ch+1}
    const int m = lane & 15;
    const int q = lane >> 4;
    f32x4 acc[2];
    acc[0] = (f32x4)0.f;
    acc[1] = (f32x4)0.f;
#pragma unroll
    for (int s = 0; s < 2; s++) {
        const float* ap = &so[(tile * 16 + m) * OSTR + s * 32 + q * 8];
        float4 v0 = *(const float4*)ap;
        float4 v1 = *(const float4*)(ap + 4);
        const float xa[8] = {v0.x, v0.y, v0.z, v0.w, v1.x, v1.y, v1.z, v1.w};
        short8v Ah, Al;
        split_frag(xa, &Ah, &Al);
#pragma unroll
        for (int c = 0; c < 2; c++) {
            int cf = ch * 2 + c;
            const unsigned short* wh = WhF2 + ((size_t)(s * 4 + cf) * 64 + lane) * 8;
            const unsigned short* wl = WlF2 + ((size_t)(s * 4 + cf) * 64 + lane) * 8;
            short8v bh = *(const short8v*)wh;
            short8v bl = *(const short8v*)wl;
            acc[c] = __builtin_amdgcn_mfma_f32_16x16x32_bf16(Ah, bh, acc[c], 0, 0, 0);
            acc[c] = __builtin_amdgcn_mfma_f32_16x16x32_bf16(Al, bh, acc[c], 0, 0, 0);
            acc[c] = __builtin_amdgcn_mfma_f32_16x16x32_bf16(Ah, bl, acc[c], 0, 0, 0);
        }
    }
#pragma unroll
    for (int r = 0; r < 4; r++) {
        int lr = tile * 16 + q * 4 + r;
        int i2 = blockIdx.x * 32 + lr;
        if (i2 < n) {
            float dr = dis[i2];
#pragma unroll
            for (int c = 0; c < 2; c++) {
                HS2[(size_t)i2 * FOUT + (ch * 2 + c) * 16 + m] = f2bf(acc[c][r] * dr);
            }
        }
    }
}

// ---- aggregate (layer 2): 8 nodes per wave, uint4 per lane ---------------
template <bool RELU>
__global__ __launch_bounds__(256) void aggregate(
    const uint4* __restrict__ hsv, const unsigned int* __restrict__ rowinfo,
    const int* __restrict__ col, const float* __restrict__ dis,
    const float* __restrict__ bias, float* __restrict__ out, int n) {
    const int wave = blockIdx.x * 4 + (threadIdx.x >> 6);
    const int lane = threadIdx.x & 63;
    const int g  = lane >> 3;
    const int jj = lane & 7;
    const int i = wave * 8 + g;
    if (i >= n) return;

    const unsigned int info = rowinfo[i];
    const int beg = (int)(info >> 8);
    const int end = beg + (int)(info & 255u);

    float a[8];
    {
        uint4 su = hsv[(size_t)i * 8 + jj];
        a[0] = bf2f(su.x & 0xFFFFu); a[1] = bf2f(su.x >> 16);
        a[2] = bf2f(su.y & 0xFFFFu); a[3] = bf2f(su.y >> 16);
        a[4] = bf2f(su.z & 0xFFFFu); a[5] = bf2f(su.z >> 16);
        a[6] = bf2f(su.w & 0xFFFFu); a[7] = bf2f(su.w >> 16);
    }

    const int gb = g << 3;
    for (int chunk = beg; chunk < end; chunk += 8) {
        int m = end - chunk;
        if (m > 8) m = 8;
        int c = (chunk + jj < end) ? col[chunk + jj] : 0;
        int q = 0;
        for (; q + 4 <= m; q += 4) {
            int s0 = __shfl(c, gb + q);
            int s1 = __shfl(c, gb + q + 1);
            int s2 = __shfl(c, gb + q + 2);
            int s3 = __shfl(c, gb + q + 3);
            uint4 u0 = hsv[(size_t)s0 * 8 + jj];
            uint4 u1 = hsv[(size_t)s1 * 8 + jj];
            uint4 u2 = hsv[(size_t)s2 * 8 + jj];
            uint4 u3 = hsv[(size_t)s3 * 8 + jj];
            acc8(u0, a);
            acc8(u1, a);
            acc8(u2, a);
            acc8(u3, a);
        }
        for (; q < m; q++) {
            int s = __shfl(c, gb + q);
            acc8(hsv[(size_t)s * 8 + jj], a);
        }
    }
    float d = dis[i];
    const float4* b4 = (const float4*)bias;
    float4 bb0 = b4[jj * 2];
    float4 bb1 = b4[jj * 2 + 1];
    float4 o0, o1;
    o0.x = d * a[0] + bb0.x; o0.y = d * a[1] + bb0.y;
    o0.z = d * a[2] + bb0.z; o0.w = d * a[3] + bb0.w;
    o1.x = d * a[4] + bb1.x; o1.y = d * a[5] + bb1.y;
    o1.z = d * a[6] + bb1.z; o1.w = d * a[7] + bb1.w;
    if (RELU) {
        o0.x = fmaxf(o0.x, 0.f); o0.y = fmaxf(o0.y, 0.f);
        o0.z = fmaxf(o0.z, 0.f); o0.w = fmaxf(o0.w, 0.f);
        o1.x = fmaxf(o1.x, 0.f); o1.y = fmaxf(o1.y, 0.f);
        o1.z = fmaxf(o1.z, 0.f); o1.w = fmaxf(o1.w, 0.f);
    }
    float4* orow = (float4*)out + (size_t)i * 16 + jj * 2;
    orow[0] = o0;
    orow[1] = o1;
}

extern "C" void kernel_launch(void* const* d_in, const int* in_sizes, int n_in,
                              void* d_out, int out_size, void* d_ws, size_t ws_size,
                              hipStream_t stream) {
    const float* x  = (const float*)d_in[0];
    const int*   ei = (const int*)d_in[1];
    const float* W1 = (const float*)d_in[2];
    const float* b1 = (const float*)d_in[3];
    const float* W2 = (const float*)d_in[4];
    const float* b2 = (const float*)d_in[5];

    const int n = in_sizes[0] / 128;
    const int E = in_sizes[1] / 2;
    const int* srcp = ei;
    const int* dstp = ei + E;

    float* out = (float*)d_out;

    const int B = (n + BW - 1) / BW;               // 782
    const int nblk = (E + CHUNK - 1) / CHUNK;      // <= 512 required

    // workspace layout
    int*            cnt     = (int*)d_ws;                     // 512*MAXB
    int*            gcnt    = cnt + 512 * MAXB;               // MAXB
    unsigned int*   rowinfo = (unsigned int*)(gcnt + MAXB);   // n
    float*          dis     = (float*)(rowinfo + n);          // n
    int*            ebuf    = (int*)(dis + n);                // B*SLAB (becomes col)
    unsigned short* hs      = (unsigned short*)(ebuf + (size_t)B * SLAB);  // n*64 bf16
    unsigned short* whf1    = hs + (size_t)n * FOUT;          // NT1*8 (16B-aligned)
    unsigned short* wlf1    = whf1 + (size_t)NT1 * 8;
    unsigned short* whf2    = wlf1 + (size_t)NT1 * 8;
    unsigned short* wlf2    = whf2 + (size_t)NT2 * 8;
    unsigned short* hs2     = wlf2 + (size_t)NT2 * 8;         // n*64 bf16

    // deterministic multisplit CSR build (no global atomics anywhere);
    // block 0 of edge_hist also pre-splits W1/W2 into bf16 hi/lo frag tables
    edge_hist<<<nblk, 512, 0, stream>>>(dstp, cnt, E, W1, W2,
                                        whf1, wlf1, whf2, wlf2);
    col_scan<<<B, 512, 0, stream>>>(cnt, nblk, gcnt);
    edge_place<<<nblk, 512, 0, stream>>>(srcp, dstp, cnt, ebuf, E);

    // CSR finalize + gemm1 fused (dis rows are bucket-local)
    csr_gemm<128><<<B, 256, 0, stream>>>(ebuf, gcnt, rowinfo, dis, n,
                                         x, whf1, wlf1, hs);

    // aggregate1 + relu + gemm2 fused (out1 lives only in LDS)
    agg_gemm<<<(n + 31) / 32, 256, 0, stream>>>(
        (const uint4*)hs, rowinfo, ebuf, dis, b1, whf2, wlf2, hs2, n);

    // layer 2 aggregate: out = dis*(hs2_self + sum hs2[nbr]) + b2
    aggregate<false><<<(n + 31) / 32, 256, 0, stream>>>(
        (const uint4*)hs2, rowinfo, ebuf, dis, b2, out, n);
}

// Round 5
// 217.546 us; speedup vs baseline: 1.0309x; 1.0309x over previous
//
#include <hip/hip_runtime.h>
#include <hip/hip_bf16.h>

// GCN 2-layer via CSR gather:
//   dis = rsqrt(indeg_by_dst + 1)
//   hs  = bf16( (x@W) * dis[row] )     (split-bf16 MFMA, fp32-accurate)
//   out[i] = act( dis[i] * (hs[i] + sum_{s in N(i)} hs[s]) + b )
// CSR build is a fully DETERMINISTIC two-pass multisplit.
// R4: latency-chain surgery.
//  - csr_gemm: X loads for k-step 0 issue BEFORE the ebuf stage (both HBM
//    latency streams in flight together through the CSR phase); remaining
//    k-steps software-pipelined (load s+1 under MFMA of s, explicit stage
//    regs, fully unrolled). MFMA order per accumulator unchanged ->
//    bit-identical hs.
//  - aggregate/agg_gemm: a block's 32 nodes are consecutive in one bucket
//    => their col ranges are ONE contiguous ebuf span. Bulk-load the span
//    into LDS coalesced, then per-edge col reads are LDS broadcasts (no
//    __shfl, no scattered col chunk loads). Edge order unchanged ->
//    bit-identical sums.

#define FOUT 64
#define BW 128        // nodes per bucket
#define BSH 7
#define MAXB 1024     // >= ceil(n/BW), power of 2
#define CHUNK 4096    // edges per hist/place block; nblk = ceil(E/CHUNK) <= 512
#define SLAB 3072     // slab capacity per bucket (mean 2046 for E=1.6M,B=782)

#define NT1 1024      // W1 frag tasks: (128/32)*4*64
#define NT2 512       // W2 frag tasks: (64/32)*4*64
#define LCOLN 2048    // LDS col-span capacity per 32-node block (mean ~512)

__device__ __forceinline__ float bf2f(unsigned int u16) {
    union { unsigned int i; float f; } c;
    c.i = u16 << 16;
    return c.f;
}
__device__ __forceinline__ unsigned short f2bf(float f) {
    union { float f; unsigned int i; } c;
    c.f = f;
    unsigned int i = c.i;
    return (unsigned short)((i + 0x7FFFu + ((i >> 16) & 1u)) >> 16);  // RN-even
}

typedef __attribute__((ext_vector_type(8))) short short8v;  // 8 bf16 = 4 VGPR
typedef __attribute__((ext_vector_type(4))) float f32x4;    // MFMA acc

// ---- split fp32x8 -> bf16 hi/lo A-fragments ------------------------------
__device__ __forceinline__ void split_frag(const float* xa, short8v* Ah, short8v* Al) {
    union { unsigned int u[4]; short8v v; } H, L;
#pragma unroll
    for (int p = 0; p < 4; p++) {
        unsigned short h0 = f2bf(xa[2 * p]);
        unsigned short h1 = f2bf(xa[2 * p + 1]);
        H.u[p] = (unsigned int)h0 | ((unsigned int)h1 << 16);
        unsigned short l0 = f2bf(xa[2 * p] - bf2f(h0));
        unsigned short l1 = f2bf(xa[2 * p + 1] - bf2f(h1));
        L.u[p] = (unsigned int)l0 | ((unsigned int)l1 << 16);
    }
    *Ah = H.v;
    *Al = L.v;
}

// ---- W -> fragment-linear bf16 hi/lo split ------------------------------
__device__ __forceinline__ void conv_w_frag(const float* __restrict__ W,
                                            unsigned short* __restrict__ WhF,
                                            unsigned short* __restrict__ WlF,
                                            int task) {
    const int lane = task & 63;
    const int cf = (task >> 6) & 3;
    const int s = task >> 8;
    const int q = lane >> 4, m = lane & 15;
#pragma unroll
    for (int j = 0; j < 8; j++) {
        int k = s * 32 + q * 8 + j;
        float x = W[(size_t)k * 64 + cf * 16 + m];
        unsigned short h = f2bf(x);
        WhF[(size_t)task * 8 + j] = h;
        WlF[(size_t)task * 8 + j] = f2bf(x - bf2f(h));
    }
}

// ---- pass A: per-block bucket histogram -> cnt[blk][bucket] --------------
__global__ __launch_bounds__(512) void edge_hist(
    const int* __restrict__ dst, int* __restrict__ cnt, int E,
    const float* __restrict__ W1, const float* __restrict__ W2,
    unsigned short* __restrict__ whf1, unsigned short* __restrict__ wlf1,
    unsigned short* __restrict__ whf2, unsigned short* __restrict__ wlf2) {
    __shared__ int h[MAXB];
    const int blk = blockIdx.x, t = threadIdx.x;
    h[t] = 0;
    h[t + 512] = 0;
    __syncthreads();
    const int e0 = blk * CHUNK;
#pragma unroll
    for (int k = 0; k < CHUNK / 512; k++) {
        int e = e0 + k * 512 + t;
        if (e < E) atomicAdd(&h[dst[e] >> BSH], 1);
    }
    if (blk == 0) {
        for (int task = t; task < NT1 + NT2; task += 512) {
            if (task < NT1) conv_w_frag(W1, whf1, wlf1, task);
            else            conv_w_frag(W2, whf2, wlf2, task - NT1);
        }
    }
    __syncthreads();
    cnt[blk * MAXB + t] = h[t];
    cnt[blk * MAXB + t + 512] = h[t + 512];
}

// ---- pass B: per-bucket exclusive scan over blocks -> absolute bases -----
__global__ __launch_bounds__(512) void col_scan(int* __restrict__ cnt, int nblk,
                                                int* __restrict__ gcnt) {
    __shared__ int ts[512];
    const int b = blockIdx.x;  // bucket
    const int t = threadIdx.x;
    int v = (t < nblk) ? cnt[t * MAXB + b] : 0;
    ts[t] = v;
    __syncthreads();
    for (int off = 1; off < 512; off <<= 1) {
        int x = (t >= off) ? ts[t - off] : 0;
        __syncthreads();
        ts[t] += x;
        __syncthreads();
    }
    if (t < nblk) cnt[t * MAXB + b] = b * SLAB + ts[t] - v;  // abs base
    if (t == 511) gcnt[b] = ts[511];                          // bucket total
}

// ---- pass C: placement at precomputed bases (no global atomics) ----------
__global__ __launch_bounds__(512) void edge_place(
    const int* __restrict__ src, const int* __restrict__ dst,
    const int* __restrict__ cnt, int* __restrict__ ebuf, int E) {
    __shared__ int lbase[MAXB];
    __shared__ int cur[MAXB];
    const int blk = blockIdx.x, t = threadIdx.x;
    lbase[t] = cnt[blk * MAXB + t];
    lbase[t + 512] = cnt[blk * MAXB + t + 512];
    cur[t] = 0;
    cur[t + 512] = 0;
    __syncthreads();
    const int e0 = blk * CHUNK;
#pragma unroll
    for (int k = 0; k < CHUNK / 512; k++) {
        int e = e0 + k * 512 + t;
        if (e < E) {
            int d = dst[e];
            int b = d >> BSH;
            int r = atomicAdd(&cur[b], 1);  // LDS only
            ebuf[lbase[b] + r] = src[e] | ((d & (BW - 1)) << 17);  // src < 2^17
        }
    }
}

// ---- fused: per-bucket CSR finalize + gemm1, latency streams overlapped --
__global__ __launch_bounds__(256) void csr_gemm(
    int* __restrict__ ebuf, const int* __restrict__ gcnt,
    unsigned int* __restrict__ rowinfo, float* __restrict__ dis, int n,
    const float* __restrict__ X, const unsigned short* __restrict__ WhF,
    const unsigned short* __restrict__ WlF, unsigned short* __restrict__ HS) {
    constexpr int K = 128;
    __shared__ int ldeg[BW];
    __shared__ float sdis[BW];
    __shared__ int wtot[2];
    const int b = blockIdx.x, t = threadIdx.x;
    const int node0 = b << BSH;
    const int nn = min(BW, n - node0);
    const int ebeg = b * SLAB;

    const int lane = t & 63;
    const int wvv = t >> 6;                 // 4 waves
    const int m = lane & 15;                // A row-in-tile / D col
    const int q = lane >> 4;                // A k-group / D row-quad
    const int tile0 = wvv * 2, tile1 = wvv * 2 + 1;
    const int r0 = node0 + tile0 * 16 + m;
    const int r1 = node0 + tile1 * 16 + m;
    const bool ok0 = (r0 < n), ok1 = (r1 < n);
    const float* xp0 = X + (size_t)r0 * K + q * 8;
    const float* xp1 = X + (size_t)r1 * K + q * 8;
    const float4 zf4 = make_float4(0.f, 0.f, 0.f, 0.f);

    // ---- X k-step-0 loads issue FIRST (in flight through the CSR phase)
    float4 c00 = zf4, c01 = zf4, c10 = zf4, c11 = zf4;
    if (ok0) { c00 = *(const float4*)xp0; c01 = *(const float4*)(xp0 + 4); }
    if (ok1) { c10 = *(const float4*)xp1; c11 = *(const float4*)(xp1 + 4); }

    // ---- ebuf slab stage (unguarded; masked after gcnt resolves)
    int raw[SLAB / 256];
#pragma unroll
    for (int k = 0; k < SLAB / 256; k++) raw[k] = ebuf[ebeg + t + k * 256];

    const int cnt = gcnt[b];
    if (t < BW) ldeg[t] = 0;
    __syncthreads();  // B1

    int w[SLAB / 256];
#pragma unroll
    for (int k = 0; k < SLAB / 256; k++) {
        w[k] = (t + k * 256 < cnt) ? raw[k] : -1;
        if (w[k] >= 0) atomicAdd(&ldeg[w[k] >> 17], 1);
    }
    __syncthreads();  // B2

    int v = 0, pv = 0;
    if (t < BW) { v = ldeg[t]; pv = v; }
#pragma unroll
    for (int d = 1; d < 64; d <<= 1) {
        int x = __shfl_up(pv, d);
        if ((lane) >= d) pv += x;
    }
    if (t < BW && lane == 63) wtot[t >> 6] = pv;
    __syncthreads();  // B3
    if (t < BW && t >= 64) pv += wtot[0];
    const int ex = pv - v;
    if (t < nn) {
        rowinfo[node0 + t] = ((unsigned int)(ebeg + ex) << 8) | (unsigned int)v;
        float dv = rsqrtf((float)v + 1.0f);  // +1 self-loop
        dis[node0 + t] = dv;
        sdis[t] = dv;
    } else if (t < BW) {
        sdis[t] = 0.f;
    }
    if (t < BW) ldeg[t] = ex;
    __syncthreads();  // B4
#pragma unroll
    for (int k = 0; k < SLAB / 256; k++)
        if (w[k] >= 0) {
            int r = atomicAdd(&ldeg[w[k] >> 17], 1);
            ebuf[ebeg + r] = w[k] & 0x1FFFF;  // ebuf becomes col
        }

    // ---- gemm1, software-pipelined over k-steps (s). Per-accumulator MFMA
    // operand order identical to prior rounds -> bit-identical hs.
    f32x4 acc0[4], acc1[4];
#pragma unroll
    for (int cf = 0; cf < 4; cf++) { acc0[cf] = (f32x4)0.f; acc1[cf] = (f32x4)0.f; }
    float4 n00, n01, n10, n11;

#define GSTEP(S)                                                                        \
    {                                                                                   \
        if ((S) + 1 < K / 32) {                                                         \
            n00 = zf4; n01 = zf4; n10 = zf4; n11 = zf4;                                 \
            if (ok0) { n00 = *(const float4*)(xp0 + ((S) + 1) * 32);                    \
                       n01 = *(const float4*)(xp0 + ((S) + 1) * 32 + 4); }              \
            if (ok1) { n10 = *(const float4*)(xp1 + ((S) + 1) * 32);                    \
                       n11 = *(const float4*)(xp1 + ((S) + 1) * 32 + 4); }              \
        }                                                                               \
        const unsigned short* wh = WhF + ((size_t)((S) * 4) * 64 + lane) * 8;           \
        const unsigned short* wl = WlF + ((size_t)((S) * 4) * 64 + lane) * 8;           \
        short8v Ah, Al;                                                                 \
        {                                                                               \
            const float xa[8] = {c00.x, c00.y, c00.z, c00.w, c01.x, c01.y, c01.z, c01.w}; \
            split_frag(xa, &Ah, &Al);                                                   \
        }                                                                               \
        _Pragma("unroll")                                                               \
        for (int cf = 0; cf < 4; cf++) {                                                \
            short8v bh = *(const short8v*)(wh + (size_t)cf * 64 * 8);                   \
            short8v bl = *(const short8v*)(wl + (size_t)cf * 64 * 8);                   \
            acc0[cf] = __builtin_amdgcn_mfma_f32_16x16x32_bf16(Ah, bh, acc0[cf], 0, 0, 0); \
            acc0[cf] = __builtin_amdgcn_mfma_f32_16x16x32_bf16(Al, bh, acc0[cf], 0, 0, 0); \
            acc0[cf] = __builtin_amdgcn_mfma_f32_16x16x32_bf16(Ah, bl, acc0[cf], 0, 0, 0); \
        }                                                                               \
        {                                                                               \
            const float xa[8] = {c10.x, c10.y, c10.z, c10.w, c11.x, c11.y, c11.z, c11.w}; \
            split_frag(xa, &Ah, &Al);                                                   \
        }                                                                               \
        _Pragma("unroll")                                                               \
        for (int cf = 0; cf < 4; cf++) {                                                \
            short8v bh = *(const short8v*)(wh + (size_t)cf * 64 * 8);                   \
            short8v bl = *(const short8v*)(wl + (size_t)cf * 64 * 8);                   \
            acc1[cf] = __builtin_amdgcn_mfma_f32_16x16x32_bf16(Ah, bh, acc1[cf], 0, 0, 0); \
            acc1[cf] = __builtin_amdgcn_mfma_f32_16x16x32_bf16(Al, bh, acc1[cf], 0, 0, 0); \
            acc1[cf] = __builtin_amdgcn_mfma_f32_16x16x32_bf16(Ah, bl, acc1[cf], 0, 0, 0); \
        }                                                                               \
        c00 = n00; c01 = n01; c10 = n10; c11 = n11;                                     \
    }
    GSTEP(0) GSTEP(1) GSTEP(2) GSTEP(3)
#undef GSTEP

#pragma unroll
    for (int r = 0; r < 4; r++) {
        int row = node0 + tile0 * 16 + q * 4 + r;
        if (row < n) {
            float dr = sdis[tile0 * 16 + q * 4 + r];
#pragma unroll
            for (int cf = 0; cf < 4; cf++)
                HS[(size_t)row * FOUT + cf * 16 + m] = f2bf(acc0[cf][r] * dr);
        }
        row = node0 + tile1 * 16 + q * 4 + r;
        if (row < n) {
            float dr = sdis[tile1 * 16 + q * 4 + r];
#pragma unroll
            for (int cf = 0; cf < 4; cf++)
                HS[(size_t)row * FOUT + cf * 16 + m] = f2bf(acc1[cf][r] * dr);
        }
    }
}

// ---- aggregate helpers ---------------------------------------------------
__device__ __forceinline__ void acc8(const uint4 u, float* a) {
    a[0] += bf2f(u.x & 0xFFFFu); a[1] += bf2f(u.x >> 16);
    a[2] += bf2f(u.y & 0xFFFFu); a[3] += bf2f(u.y >> 16);
    a[4] += bf2f(u.z & 0xFFFFu); a[5] += bf2f(u.z >> 16);
    a[6] += bf2f(u.w & 0xFFFFu); a[7] += bf2f(u.w >> 16);
}

// Cooperative col staging: a block's 32 nodes are consecutive within one
// bucket, so their col ranges form one contiguous ebuf span. One coalesced
// burst into LDS; per-edge col reads become LDS broadcasts.
__device__ __forceinline__ void stage_cols(
    const unsigned int* __restrict__ rowinfo, const int* __restrict__ col,
    int* lcol, int* sbs, int i0, int n, int tid) {
    if (tid == 0) {
        int last = min(i0 + 31, n - 1);
        unsigned int r0 = rowinfo[i0];
        unsigned int rl = rowinfo[last];
        int base = (int)(r0 >> 8);
        sbs[0] = base;
        sbs[1] = (int)(rl >> 8) + (int)(rl & 255u) - base;
    }
    __syncthreads();
    const int span = sbs[1];
    if (span <= LCOLN) {
        const int base = sbs[0];
        for (int k = tid; k < span; k += 256) lcol[k] = col[base + k];
    }
    __syncthreads();
}

// ---- fused: aggregate1 (+relu) -> LDS -> gemm2 -> hs2 --------------------
#define OSTR 68
__global__ __launch_bounds__(256) void agg_gemm(
    const uint4* __restrict__ hsv, const unsigned int* __restrict__ rowinfo,
    const int* __restrict__ col, const float* __restrict__ dis,
    const float* __restrict__ bias,
    const unsigned short* __restrict__ WhF2, const unsigned short* __restrict__ WlF2,
    unsigned short* __restrict__ HS2, int n) {
    __shared__ float so[32 * OSTR];  // 8704 B
    __shared__ int lcol[LCOLN];      // 8192 B
    __shared__ int sbs[2];
    const int tid = threadIdx.x;
    const int wv = tid >> 6;
    const int lane = tid & 63;
    const int g = lane >> 3;
    const int jj = lane & 7;
    const int lrow = wv * 8 + g;
    const int i0 = blockIdx.x * 32;
    const int i = i0 + lrow;

    const unsigned int info = (i < n) ? rowinfo[i] : 0u;
    uint4 su = make_uint4(0u, 0u, 0u, 0u);
    if (i < n) su = hsv[(size_t)i * 8 + jj];  // self-loop term, issued early

    stage_cols(rowinfo, col, lcol, sbs, i0, n, tid);
    const int base = sbs[0], span = sbs[1];
    const bool uselds = (span <= LCOLN);

    float o[8];
#pragma unroll
    for (int p = 0; p < 8; p++) o[p] = 0.f;

    if (i < n) {
        const int beg = (int)(info >> 8);
        const int deg = (int)(info & 255u);
        const int off = beg - base;

        float a[8];
        a[0] = bf2f(su.x & 0xFFFFu); a[1] = bf2f(su.x >> 16);
        a[2] = bf2f(su.y & 0xFFFFu); a[3] = bf2f(su.y >> 16);
        a[4] = bf2f(su.z & 0xFFFFu); a[5] = bf2f(su.z >> 16);
        a[6] = bf2f(su.w & 0xFFFFu); a[7] = bf2f(su.w >> 16);

        int qq = 0;
        for (; qq + 4 <= deg; qq += 4) {
            int s0 = uselds ? lcol[off + qq]     : col[beg + qq];
            int s1 = uselds ? lcol[off + qq + 1] : col[beg + qq + 1];
            int s2 = uselds ? lcol[off + qq + 2] : col[beg + qq + 2];
            int s3 = uselds ? lcol[off + qq + 3] : col[beg + qq + 3];
            uint4 u0 = hsv[(size_t)s0 * 8 + jj];
            uint4 u1 = hsv[(size_t)s1 * 8 + jj];
            uint4 u2 = hsv[(size_t)s2 * 8 + jj];
            uint4 u3 = hsv[(size_t)s3 * 8 + jj];
            acc8(u0, a); acc8(u1, a); acc8(u2, a); acc8(u3, a);
        }
        for (; qq < deg; qq++) {
            int s = uselds ? lcol[off + qq] : col[beg + qq];
            acc8(hsv[(size_t)s * 8 + jj], a);
        }
        float d = dis[i];
        const float4* b4 = (const float4*)bias;
        float4 bb0 = b4[jj * 2];
        float4 bb1 = b4[jj * 2 + 1];
        o[0] = fmaxf(d * a[0] + bb0.x, 0.f);
        o[1] = fmaxf(d * a[1] + bb0.y, 0.f);
        o[2] = fmaxf(d * a[2] + bb0.z, 0.f);
        o[3] = fmaxf(d * a[3] + bb0.w, 0.f);
        o[4] = fmaxf(d * a[4] + bb1.x, 0.f);
        o[5] = fmaxf(d * a[5] + bb1.y, 0.f);
        o[6] = fmaxf(d * a[6] + bb1.z, 0.f);
        o[7] = fmaxf(d * a[7] + bb1.w, 0.f);
    }
    {
        float* sp = &so[lrow * OSTR + jj * 8];
        *(float4*)sp = make_float4(o[0], o[1], o[2], o[3]);
        *(float4*)(sp + 4) = make_float4(o[4], o[5], o[6], o[7]);
    }
    __syncthreads();

    // ---- gemm2 from LDS: hs2 = bf16((out1 @ W2) * dis) ------------------
    const int tile = wv >> 1;
    const int ch = wv & 1;
    const int m = lane & 15;
    const int q = lane >> 4;
    f32x4 acc[2];
    acc[0] = (f32x4)0.f;
    acc[1] = (f32x4)0.f;
#pragma unroll
    for (int s = 0; s < 2; s++) {
        const float* ap = &so[(tile * 16 + m) * OSTR + s * 32 + q * 8];
        float4 v0 = *(const float4*)ap;
        float4 v1 = *(const float4*)(ap + 4);
        const float xa[8] = {v0.x, v0.y, v0.z, v0.w, v1.x, v1.y, v1.z, v1.w};
        short8v Ah, Al;
        split_frag(xa, &Ah, &Al);
#pragma unroll
        for (int c = 0; c < 2; c++) {
            int cf = ch * 2 + c;
            const unsigned short* wh = WhF2 + ((size_t)(s * 4 + cf) * 64 + lane) * 8;
            const unsigned short* wl = WlF2 + ((size_t)(s * 4 + cf) * 64 + lane) * 8;
            short8v bh = *(const short8v*)wh;
            short8v bl = *(const short8v*)wl;
            acc[c] = __builtin_amdgcn_mfma_f32_16x16x32_bf16(Ah, bh, acc[c], 0, 0, 0);
            acc[c] = __builtin_amdgcn_mfma_f32_16x16x32_bf16(Al, bh, acc[c], 0, 0, 0);
            acc[c] = __builtin_amdgcn_mfma_f32_16x16x32_bf16(Ah, bl, acc[c], 0, 0, 0);
        }
    }
#pragma unroll
    for (int r = 0; r < 4; r++) {
        int lr = tile * 16 + q * 4 + r;
        int i2 = blockIdx.x * 32 + lr;
        if (i2 < n) {
            float dr = dis[i2];
#pragma unroll
            for (int c = 0; c < 2; c++) {
                HS2[(size_t)i2 * FOUT + (ch * 2 + c) * 16 + m] = f2bf(acc[c][r] * dr);
            }
        }
    }
}

// ---- aggregate (layer 2): LDS-staged cols, 8 nodes per wave --------------
template <bool RELU>
__global__ __launch_bounds__(256) void aggregate(
    const uint4* __restrict__ hsv, const unsigned int* __restrict__ rowinfo,
    const int* __restrict__ col, const float* __restrict__ dis,
    const float* __restrict__ bias, float* __restrict__ out, int n) {
    __shared__ int lcol[LCOLN];
    __shared__ int sbs[2];
    const int tid = threadIdx.x;
    const int wv = tid >> 6;
    const int lane = tid & 63;
    const int g = lane >> 3;
    const int jj = lane & 7;
    const int i0 = blockIdx.x * 32;
    const int i = i0 + wv * 8 + g;

    const unsigned int info = (i < n) ? rowinfo[i] : 0u;
    uint4 su = make_uint4(0u, 0u, 0u, 0u);
    if (i < n) su = hsv[(size_t)i * 8 + jj];

    stage_cols(rowinfo, col, lcol, sbs, i0, n, tid);
    const int base = sbs[0], span = sbs[1];
    const bool uselds = (span <= LCOLN);

    if (i >= n) return;  // all barriers done

    const int beg = (int)(info >> 8);
    const int deg = (int)(info & 255u);
    const int off = beg - base;

    float a[8];
    a[0] = bf2f(su.x & 0xFFFFu); a[1] = bf2f(su.x >> 16);
    a[2] = bf2f(su.y & 0xFFFFu); a[3] = bf2f(su.y >> 16);
    a[4] = bf2f(su.z & 0xFFFFu); a[5] = bf2f(su.z >> 16);
    a[6] = bf2f(su.w & 0xFFFFu); a[7] = bf2f(su.w >> 16);

    int qq = 0;
    for (; qq + 4 <= deg; qq += 4) {
        int s0 = uselds ? lcol[off + qq]     : col[beg + qq];
        int s1 = uselds ? lcol[off + qq + 1] : col[beg + qq + 1];
        int s2 = uselds ? lcol[off + qq + 2] : col[beg + qq + 2];
        int s3 = uselds ? lcol[off + qq + 3] : col[beg + qq + 3];
        uint4 u0 = hsv[(size_t)s0 * 8 + jj];
        uint4 u1 = hsv[(size_t)s1 * 8 + jj];
        uint4 u2 = hsv[(size_t)s2 * 8 + jj];
        uint4 u3 = hsv[(size_t)s3 * 8 + jj];
        acc8(u0, a); acc8(u1, a); acc8(u2, a); acc8(u3, a);
    }
    for (; qq < deg; qq++) {
        int s = uselds ? lcol[off + qq] : col[beg + qq];
        acc8(hsv[(size_t)s * 8 + jj], a);
    }
    float d = dis[i];
    const float4* b4 = (const float4*)bias;
    float4 bb0 = b4[jj * 2];
    float4 bb1 = b4[jj * 2 + 1];
    float4 o0, o1;
    o0.x = d * a[0] + bb0.x; o0.y = d * a[1] + bb0.y;
    o0.z = d * a[2] + bb0.z; o0.w = d * a[3] + bb0.w;
    o1.x = d * a[4] + bb1.x; o1.y = d * a[5] + bb1.y;
    o1.z = d * a[6] + bb1.z; o1.w = d * a[7] + bb1.w;
    if (RELU) {
        o0.x = fmaxf(o0.x, 0.f); o0.y = fmaxf(o0.y, 0.f);
        o0.z = fmaxf(o0.z, 0.f); o0.w = fmaxf(o0.w, 0.f);
        o1.x = fmaxf(o1.x, 0.f); o1.y = fmaxf(o1.y, 0.f);
        o1.z = fmaxf(o1.z, 0.f); o1.w = fmaxf(o1.w, 0.f);
    }
    float4* orow = (float4*)out + (size_t)i * 16 + jj * 2;
    orow[0] = o0;
    orow[1] = o1;
}

extern "C" void kernel_launch(void* const* d_in, const int* in_sizes, int n_in,
                              void* d_out, int out_size, void* d_ws, size_t ws_size,
                              hipStream_t stream) {
    const float* x  = (const float*)d_in[0];
    const int*   ei = (const int*)d_in[1];
    const float* W1 = (const float*)d_in[2];
    const float* b1 = (const float*)d_in[3];
    const float* W2 = (const float*)d_in[4];
    const float* b2 = (const float*)d_in[5];

    const int n = in_sizes[0] / 128;
    const int E = in_sizes[1] / 2;
    const int* srcp = ei;
    const int* dstp = ei + E;

    float* out = (float*)d_out;

    const int B = (n + BW - 1) / BW;               // 782
    const int nblk = (E + CHUNK - 1) / CHUNK;      // <= 512 required

    // workspace layout
    int*            cnt     = (int*)d_ws;                     // 512*MAXB
    int*            gcnt    = cnt + 512 * MAXB;               // MAXB
    unsigned int*   rowinfo = (unsigned int*)(gcnt + MAXB);   // n
    float*          dis     = (float*)(rowinfo + n);          // n
    int*            ebuf    = (int*)(dis + n);                // B*SLAB (becomes col)
    unsigned short* hs      = (unsigned short*)(ebuf + (size_t)B * SLAB);  // n*64 bf16
    unsigned short* whf1    = hs + (size_t)n * FOUT;          // NT1*8 (16B-aligned)
    unsigned short* wlf1    = whf1 + (size_t)NT1 * 8;
    unsigned short* whf2    = wlf1 + (size_t)NT1 * 8;
    unsigned short* wlf2    = whf2 + (size_t)NT2 * 8;
    unsigned short* hs2     = wlf2 + (size_t)NT2 * 8;         // n*64 bf16

    edge_hist<<<nblk, 512, 0, stream>>>(dstp, cnt, E, W1, W2,
                                        whf1, wlf1, whf2, wlf2);
    col_scan<<<B, 512, 0, stream>>>(cnt, nblk, gcnt);
    edge_place<<<nblk, 512, 0, stream>>>(srcp, dstp, cnt, ebuf, E);

    // CSR finalize + gemm1 fused, X/ebuf latency streams overlapped
    csr_gemm<<<B, 256, 0, stream>>>(ebuf, gcnt, rowinfo, dis, n,
                                    x, whf1, wlf1, hs);

    // aggregate1 + relu + gemm2 fused (out1 lives only in LDS)
    agg_gemm<<<(n + 31) / 32, 256, 0, stream>>>(
        (const uint4*)hs, rowinfo, ebuf, dis, b1, whf2, wlf2, hs2, n);

    // layer 2 aggregate: out = dis*(hs2_self + sum hs2[nbr]) + b2
    aggregate<false><<<(n + 31) / 32, 256, 0, stream>>>(
        (const uint4*)hs2, rowinfo, ebuf, dis, b2, out, n);
}